// Round 2
// baseline (25232.324 us; speedup 1.0000x reference)
//
#include <hip/hip_runtime.h>

// Llama-style forward: B=2,T=1024, D=768, H=12,HS=64, NKV=3 (GQA rep 4),
// L=12, I=2048, V=50257. ALL float tensors are fp32 (threshold analysis:
// 2%-of-maxref, no bf16 floor), idx int32, output fp32 logits (B,T,V).

#define NTOK 2048      // B*T
#define DM   768
#define DKV  192       // NKV*HS
#define TSEQ 1024
#define NH   12
#define HSZ  64
#define NKVH 3
#define IDIM 2048
#define VOC  50257
#define NLAY 12

// ---------------- embedding gather ----------------
__global__ void embed_kernel(const int* __restrict__ idx,
                             const float* __restrict__ embed,
                             float* __restrict__ x) {
    int tok = blockIdx.x;
    int row = idx[tok];
    for (int d = threadIdx.x; d < DM; d += 256)
        x[(size_t)tok * DM + d] = embed[(size_t)row * DM + d];
}

// ---------------- RMSNorm ----------------
__global__ void rmsnorm_kernel(const float* __restrict__ x,
                               const float* __restrict__ w,
                               float* __restrict__ o) {
    int tok = blockIdx.x;
    const float* xr = x + (size_t)tok * DM;
    float ss = 0.f;
    for (int d = threadIdx.x; d < DM; d += 256) { float v = xr[d]; ss += v * v; }
    __shared__ float red[256];
    red[threadIdx.x] = ss;
    __syncthreads();
    for (int s = 128; s > 0; s >>= 1) {
        if (threadIdx.x < s) red[threadIdx.x] += red[threadIdx.x + s];
        __syncthreads();
    }
    float rs = rsqrtf(red[0] / (float)DM + 1e-6f);
    for (int d = threadIdx.x; d < DM; d += 256)
        o[(size_t)tok * DM + d] = xr[d] * rs * w[d];
}

// ---------------- GEMM: C[M,N] = A[M,K] * B (+C), all fp32 ----------------
// BT=false: B is KxN row-major. BT=true: B is NxK row-major (B transposed).
// M multiple of 64, K multiple of 16; N guarded.
template<bool RES, bool BT>
__global__ void gemm_kernel(const float* __restrict__ A,
                            const float* __restrict__ B,
                            float* __restrict__ C, int M, int N, int K) {
    __shared__ float As[16][68];
    __shared__ float Bs[16][68];
    int t  = threadIdx.x;
    int m0 = blockIdx.y * 64;
    int n0 = blockIdx.x * 64;
    int tx = t & 15, ty = t >> 4;
    float acc[4][4] = {};
    for (int k0 = 0; k0 < K; k0 += 16) {
#pragma unroll
        for (int i = 0; i < 4; i++) {
            int id = t + 256 * i;
            int kk = id & 15, mm = id >> 4;
            As[kk][mm] = A[(size_t)(m0 + mm) * K + (k0 + kk)];
        }
#pragma unroll
        for (int i = 0; i < 4; i++) {
            int id = t + 256 * i;
            if (BT) {
                int kk = id & 15, nn = id >> 4;
                int n = n0 + nn;
                Bs[kk][nn] = (n < N) ? B[(size_t)n * K + (k0 + kk)] : 0.f;
            } else {
                int nn = id & 63, kk = id >> 6;
                int n = n0 + nn;
                Bs[kk][nn] = (n < N) ? B[(size_t)(k0 + kk) * N + n] : 0.f;
            }
        }
        __syncthreads();
#pragma unroll
        for (int kk = 0; kk < 16; kk++) {
            float4 av = *(const float4*)&As[kk][ty * 4];
            float4 bv = *(const float4*)&Bs[kk][tx * 4];
            float a_[4] = {av.x, av.y, av.z, av.w};
            float b_[4] = {bv.x, bv.y, bv.z, bv.w};
#pragma unroll
            for (int i = 0; i < 4; i++)
#pragma unroll
                for (int j = 0; j < 4; j++)
                    acc[i][j] += a_[i] * b_[j];
        }
        __syncthreads();
    }
#pragma unroll
    for (int i = 0; i < 4; i++) {
        int m = m0 + ty * 4 + i;
#pragma unroll
        for (int j = 0; j < 4; j++) {
            int n = n0 + tx * 4 + j;
            if (n < N) {
                size_t o = (size_t)m * N + n;
                float v = acc[i][j];
                if (RES) v += C[o];
                C[o] = v;
            }
        }
    }
}

// ---------------- RoPE (rotate-half, half=32, full head dim 64) ----------------
__global__ void rope_kernel(float* __restrict__ p, int nheads, int total) {
    int gid = blockIdx.x * 256 + threadIdx.x;
    if (gid >= total) return;
    int j    = gid & 31;
    int rest = gid >> 5;
    int h    = rest % nheads;
    int tok  = rest / nheads;
    int pos  = tok & (TSEQ - 1);
    float freq = powf(10000.f, (float)j * (1.f / 32.f));
    float ang  = (float)pos / freq;
    float s = sinf(ang), c = cosf(ang);
    float* row = p + (size_t)tok * (nheads * HSZ) + h * HSZ;
    float a = row[j], b = row[j + 32];
    row[j]      = a * c - b * s;
    row[j + 32] = b * c + a * s;
}

// ---------------- causal attention, online softmax ----------------
// one wave per (b,h,tq) query row; lanes span the 64-dim head
__global__ void attn_kernel(const float* __restrict__ q,
                            const float* __restrict__ k,
                            const float* __restrict__ v,
                            float* __restrict__ y) {
    int lane = threadIdx.x & 63;
    int wv   = threadIdx.x >> 6;
    int row  = blockIdx.x * 4 + wv;          // [0, B*H*T)
    int tq   = row & (TSEQ - 1);
    int h    = (row >> 10) % NH;
    int b    = row / (TSEQ * NH);
    int kvh  = h % NKVH;
    size_t tok = (size_t)b * TSEQ + tq;
    float qd = q[tok * DM + h * HSZ + lane] * 0.125f;   // 1/sqrt(64)
    const float* kb = k + (size_t)b * TSEQ * DKV + kvh * HSZ + lane;
    const float* vb = v + (size_t)b * TSEQ * DKV + kvh * HSZ + lane;
    float m = -3.0e38f, l = 0.f, acc = 0.f;
    for (int j = 0; j <= tq; j++) {
        float s = qd * kb[(size_t)j * DKV];
#pragma unroll
        for (int off = 32; off; off >>= 1) s += __shfl_xor(s, off, 64);
        float mn   = fmaxf(m, s);
        float corr = expf(m - mn);
        float p    = expf(s - mn);
        l   = l * corr + p;
        acc = acc * corr + p * vb[(size_t)j * DKV];
        m = mn;
    }
    y[tok * DM + h * HSZ + lane] = acc / l;
}

// ---------------- SwiGLU elementwise ----------------
__global__ void silu_mul_kernel(float* __restrict__ g,
                                const float* __restrict__ u, int n) {
    int i = blockIdx.x * 256 + threadIdx.x;
    if (i < n) {
        float x = g[i];
        g[i] = (x / (1.f + expf(-x))) * u[i];
    }
}

extern "C" void kernel_launch(void* const* d_in, const int* in_sizes, int n_in,
                              void* d_out, int out_size, void* d_ws, size_t ws_size,
                              hipStream_t stream) {
    const int*   idx    = (const int*)d_in[0];
    const float* embed  = (const float*)d_in[1];
    const float* ln1_w  = (const float*)d_in[2];
    const float* q_w    = (const float*)d_in[3];
    const float* k_w    = (const float*)d_in[4];
    const float* v_w    = (const float*)d_in[5];
    const float* o_w    = (const float*)d_in[6];
    const float* ln2_w  = (const float*)d_in[7];
    const float* gate_w = (const float*)d_in[8];
    const float* up_w   = (const float*)d_in[9];
    const float* down_w = (const float*)d_in[10];
    const float* norm_w = (const float*)d_in[11];
    float* out = (float*)d_out;

    float* x  = (float*)d_ws;                 // NTOK*DM
    float* h  = x  + (size_t)NTOK * DM;       // NTOK*DM
    float* qb = h  + (size_t)NTOK * DM;       // NTOK*DM
    float* kb = qb + (size_t)NTOK * DM;       // NTOK*DKV
    float* vb = kb + (size_t)NTOK * DKV;      // NTOK*DKV
    float* yb = vb + (size_t)NTOK * DKV;      // NTOK*DM
    // MLP buffers alias the attention buffers (disjoint in time):
    float* gb = qb;                           // NTOK*IDIM
    float* ub = qb + (size_t)NTOK * IDIM;     // NTOK*IDIM

    dim3 blk(256);
    embed_kernel<<<NTOK, blk, 0, stream>>>(idx, embed, x);
    for (int l = 0; l < NLAY; l++) {
        rmsnorm_kernel<<<NTOK, blk, 0, stream>>>(x, ln1_w + (size_t)l * DM, h);
        gemm_kernel<false,false><<<dim3(DM/64,  NTOK/64), blk, 0, stream>>>(h, q_w + (size_t)l*DM*DM,  qb, NTOK, DM,  DM);
        gemm_kernel<false,false><<<dim3(DKV/64, NTOK/64), blk, 0, stream>>>(h, k_w + (size_t)l*DM*DKV, kb, NTOK, DKV, DM);
        gemm_kernel<false,false><<<dim3(DKV/64, NTOK/64), blk, 0, stream>>>(h, v_w + (size_t)l*DM*DKV, vb, NTOK, DKV, DM);
        rope_kernel<<<(NTOK*NH*32   + 255)/256, blk, 0, stream>>>(qb, NH,   NTOK*NH*32);
        rope_kernel<<<(NTOK*NKVH*32 + 255)/256, blk, 0, stream>>>(kb, NKVH, NTOK*NKVH*32);
        attn_kernel<<<NTOK*NH/4, blk, 0, stream>>>(qb, kb, vb, yb);
        gemm_kernel<true,false><<<dim3(DM/64, NTOK/64), blk, 0, stream>>>(yb, o_w + (size_t)l*DM*DM, x, NTOK, DM, DM);
        rmsnorm_kernel<<<NTOK, blk, 0, stream>>>(x, ln2_w + (size_t)l * DM, h);
        gemm_kernel<false,false><<<dim3(IDIM/64, NTOK/64), blk, 0, stream>>>(h, gate_w + (size_t)l*DM*IDIM, gb, NTOK, IDIM, DM);
        gemm_kernel<false,false><<<dim3(IDIM/64, NTOK/64), blk, 0, stream>>>(h, up_w   + (size_t)l*DM*IDIM, ub, NTOK, IDIM, DM);
        silu_mul_kernel<<<(NTOK*IDIM + 255)/256, blk, 0, stream>>>(gb, ub, NTOK*IDIM);
        gemm_kernel<true,false><<<dim3(DM/64, NTOK/64), blk, 0, stream>>>(gb, down_w + (size_t)l*IDIM*DM, x, NTOK, DM, IDIM);
    }
    rmsnorm_kernel<<<NTOK, blk, 0, stream>>>(x, norm_w, h);
    gemm_kernel<false,true><<<dim3((VOC+63)/64, NTOK/64), blk, 0, stream>>>(h, embed, out, NTOK, VOC, DM);
}